// Round 1
// baseline (1216.263 us; speedup 1.0000x reference)
//
#include <hip/hip_runtime.h>

// Problem constants (match reference)
#define SEQ 1024
#define BSZ 2
#define DIM 512
#define NH  4                    // NQ == NK == 4
#define RSQRT_D 0.04419417382415922f   // 1/sqrt(512)
#define EPS 1e-12f

#define PROJ_ELEMS ((size_t)BSZ*NH*SEQ*DIM)          // 4,194,304 floats
#define P_ELEMS    ((size_t)BSZ*NH*NH*SEQ*SEQ)       // 33,554,432 floats

// ---------------------------------------------------------------------------
// Projection: out[b][g][s][d] = sum_c x[s][b][c] * W[g*DIM+d][c] + bias[g*DIM+d]
// NT GEMM, M=2048 rows r=(b,s), N=2048 cols n=(g,d), K=512.
// BM=BN=64, BK=16, 256 threads, 4x4 micro-tile.
// ---------------------------------------------------------------------------
__global__ __launch_bounds__(256) void proj_kernel(
    const float* __restrict__ x, const float* __restrict__ W,
    const float* __restrict__ bias, float* __restrict__ out)
{
    __shared__ float As[16][68];   // [k][m], padded stride 68 (272B, 16B aligned)
    __shared__ float Bs[16][68];   // [k][n]
    const int t  = threadIdx.x;
    const int tx = t & 15, ty = t >> 4;
    const int n0 = blockIdx.x * 64;
    const int r0 = blockIdx.y * 64;

    const int lrow = t >> 2;        // 0..63
    const int lc   = (t & 3) * 4;   // 0,4,8,12
    const int r  = r0 + lrow;
    const int rb = r >> 10, rs = r & (SEQ - 1);
    const float* Arow = x + (size_t)rs * (BSZ*DIM) + (size_t)rb * DIM + lc;
    const float* Brow = W + (size_t)(n0 + lrow) * DIM + lc;

    float acc[4][4] = {};
    for (int c0 = 0; c0 < DIM; c0 += 16) {
        float4 av = *(const float4*)(Arow + c0);
        float4 bv = *(const float4*)(Brow + c0);
        __syncthreads();
        As[lc+0][lrow]=av.x; As[lc+1][lrow]=av.y; As[lc+2][lrow]=av.z; As[lc+3][lrow]=av.w;
        Bs[lc+0][lrow]=bv.x; Bs[lc+1][lrow]=bv.y; Bs[lc+2][lrow]=bv.z; Bs[lc+3][lrow]=bv.w;
        __syncthreads();
        #pragma unroll
        for (int k = 0; k < 16; ++k) {
            float4 a  = *(const float4*)&As[k][ty*4];
            float4 b4 = *(const float4*)&Bs[k][tx*4];
            const float aa[4] = {a.x, a.y, a.z, a.w};
            const float bb[4] = {b4.x, b4.y, b4.z, b4.w};
            #pragma unroll
            for (int i = 0; i < 4; ++i)
                #pragma unroll
                for (int j = 0; j < 4; ++j)
                    acc[i][j] = fmaf(aa[i], bb[j], acc[i][j]);
        }
    }
    #pragma unroll
    for (int i = 0; i < 4; ++i) {
        const int rr = r0 + ty*4 + i;
        const int b = rr >> 10, s = rr & (SEQ - 1);
        const int n = n0 + tx*4;
        const int g = n >> 9, d = n & (DIM - 1);
        float4 o = make_float4(acc[i][0] + bias[n+0], acc[i][1] + bias[n+1],
                               acc[i][2] + bias[n+2], acc[i][3] + bias[n+3]);
        *(float4*)&out[(((size_t)b*NH + g)*SEQ + s)*DIM + d] = o;
    }
}

// ---------------------------------------------------------------------------
// Scores: P[b][h][j][s] = relu( mask(t<=s) * <Kp[b][j], Qp[b][h][s]> / sqrt(D) )
// plus atomic column-sum into denom[b][h][s].  j=(i,t), t=j&1023.
// NT GEMM per (b,h): M=4096 (j), N=1024 (s), K=512. BM=BN=128, BK=8, 8x8 micro.
// Causal skip: block dead iff t0 > s0+127.
// ---------------------------------------------------------------------------
__global__ __launch_bounds__(256) void scores_kernel(
    const float* __restrict__ Kp, const float* __restrict__ Qp,
    float* __restrict__ P, float* __restrict__ denom)
{
    const int bh = blockIdx.z;            // b*4+h
    const int b  = bh >> 2;
    const int s0 = blockIdx.x * 128;
    const int j0 = blockIdx.y * 128;
    const int t0 = j0 & (SEQ - 1);
    if (t0 > s0 + 127) return;            // fully masked: P never read here

    __shared__ float As[8][132];          // [k][j-local]
    __shared__ float Bs[8][132];          // [k][s-local]
    __shared__ float colsum[128];

    const int t  = threadIdx.x;
    const int tx = t & 15, ty = t >> 4;
    const int lrow = t >> 1;              // 0..127
    const int lc   = (t & 1) * 4;         // 0 or 4

    const float* A = Kp + ((size_t)b * (NH*SEQ) + j0 + lrow) * DIM + lc;
    const float* B = Qp + ((size_t)bh * SEQ + s0 + lrow) * DIM + lc;

    float acc[8][8] = {};
    for (int c0 = 0; c0 < DIM; c0 += 8) {
        float4 av = *(const float4*)(A + c0);
        float4 bv = *(const float4*)(B + c0);
        __syncthreads();
        As[lc+0][lrow]=av.x; As[lc+1][lrow]=av.y; As[lc+2][lrow]=av.z; As[lc+3][lrow]=av.w;
        Bs[lc+0][lrow]=bv.x; Bs[lc+1][lrow]=bv.y; Bs[lc+2][lrow]=bv.z; Bs[lc+3][lrow]=bv.w;
        __syncthreads();
        #pragma unroll
        for (int k = 0; k < 8; ++k) {
            float a[8], bb[8];
            *(float4*)&a[0]  = *(const float4*)&As[k][ty*8];
            *(float4*)&a[4]  = *(const float4*)&As[k][ty*8+4];
            *(float4*)&bb[0] = *(const float4*)&Bs[k][tx*8];
            *(float4*)&bb[4] = *(const float4*)&Bs[k][tx*8+4];
            #pragma unroll
            for (int i = 0; i < 8; ++i)
                #pragma unroll
                for (int j = 0; j < 8; ++j)
                    acc[i][j] = fmaf(a[i], bb[j], acc[i][j]);
        }
    }

    if (t < 128) colsum[t] = 0.0f;
    __syncthreads();

    float colp[8] = {};
    #pragma unroll
    for (int i = 0; i < 8; ++i) {
        const int j  = j0 + ty*8 + i;
        const int tt = j & (SEQ - 1);
        float v[8];
        #pragma unroll
        for (int jj = 0; jj < 8; ++jj) {
            const int s = s0 + tx*8 + jj;
            float sc = acc[i][jj] * RSQRT_D;
            sc = (tt <= s && sc > 0.0f) ? sc : 0.0f;
            v[jj] = sc;
            colp[jj] += sc;
        }
        float* prow = P + ((size_t)bh * (NH*SEQ) + j) * SEQ + s0 + tx*8;
        *(float4*)&prow[0] = make_float4(v[0], v[1], v[2], v[3]);
        *(float4*)&prow[4] = make_float4(v[4], v[5], v[6], v[7]);
    }
    #pragma unroll
    for (int jj = 0; jj < 8; ++jj)
        atomicAdd(&colsum[tx*8 + jj], colp[jj]);
    __syncthreads();
    if (t < 128)
        atomicAdd(&denom[(size_t)bh*SEQ + s0 + t], colsum[t]);
}

// ---------------------------------------------------------------------------
// PV: Opre[b][s][h*DIM+d] = (1/(denom[b][h][s]+EPS)) * sum_j P[b][h][j][s]*Vp[b][j][d]
// TN GEMM per (b,h): M=1024 (s), N=512 (d), K=4096 (j). BM=BN=64, BK=16, 4x4 micro.
// j-loop bound matches scores kernel's skip granularity (128-aligned).
// ---------------------------------------------------------------------------
__global__ __launch_bounds__(256) void pv_kernel(
    const float* __restrict__ P, const float* __restrict__ Vp,
    const float* __restrict__ denom, float* __restrict__ Opre)
{
    const int bh = blockIdx.z;
    const int b = bh >> 2, h = bh & 3;
    const int d0 = blockIdx.x * 64;
    const int s0 = blockIdx.y * 64;
    const int Tmax = min(SEQ, (s0 & ~127) + 128);   // valid (written) P region

    __shared__ float As[16][68];   // [j-local][s-local]
    __shared__ float Bs[16][68];   // [j-local][d-local]
    const int t  = threadIdx.x;
    const int tx = t & 15, ty = t >> 4;
    const int jr = t >> 4;          // 0..15
    const int sc = (t & 15) * 4;    // 0..60

    const float* Abase = P  + (size_t)bh * (NH*SEQ) * SEQ;
    const float* Bbase = Vp + (size_t)b  * (NH*SEQ) * DIM;

    float acc[4][4] = {};
    for (int seg = 0; seg < NH; ++seg) {
        for (int tt0 = 0; tt0 < Tmax; tt0 += 16) {
            const int j0 = seg*SEQ + tt0;
            float4 av = *(const float4*)&Abase[(size_t)(j0+jr)*SEQ + s0 + sc];
            float4 bv = *(const float4*)&Bbase[(size_t)(j0+jr)*DIM + d0 + sc];
            __syncthreads();
            *(float4*)&As[jr][sc] = av;
            *(float4*)&Bs[jr][sc] = bv;
            __syncthreads();
            #pragma unroll
            for (int k = 0; k < 16; ++k) {
                float4 a  = *(const float4*)&As[k][ty*4];
                float4 b4 = *(const float4*)&Bs[k][tx*4];
                const float aa[4] = {a.x, a.y, a.z, a.w};
                const float bb[4] = {b4.x, b4.y, b4.z, b4.w};
                #pragma unroll
                for (int i = 0; i < 4; ++i)
                    #pragma unroll
                    for (int j = 0; j < 4; ++j)
                        acc[i][j] = fmaf(aa[i], bb[j], acc[i][j]);
            }
        }
    }
    #pragma unroll
    for (int i = 0; i < 4; ++i) {
        const int s = s0 + ty*4 + i;
        const float scale = 1.0f / (denom[(size_t)bh*SEQ + s] + EPS);
        float4 o = make_float4(acc[i][0]*scale, acc[i][1]*scale,
                               acc[i][2]*scale, acc[i][3]*scale);
        *(float4*)&Opre[((size_t)b*SEQ + s)*(NH*DIM) + h*DIM + d0 + tx*4] = o;
    }
}

// ---------------------------------------------------------------------------
// Output projection: out[s][b][e] = sum_hd Opre[(b,s)][hd] * WO[e][hd] + WOb[e]
// NT GEMM, M=2048 r=(b,s), N=512 (e), K=2048. BM=BN=64, BK=16, 4x4 micro.
// ---------------------------------------------------------------------------
__global__ __launch_bounds__(256) void outproj_kernel(
    const float* __restrict__ Opre, const float* __restrict__ WO,
    const float* __restrict__ bias, float* __restrict__ out)
{
    __shared__ float As[16][68];
    __shared__ float Bs[16][68];
    const int t  = threadIdx.x;
    const int tx = t & 15, ty = t >> 4;
    const int n0 = blockIdx.x * 64;   // e
    const int r0 = blockIdx.y * 64;   // (b,s)
    const int lrow = t >> 2, lc = (t & 3) * 4;

    const float* Arow = Opre + (size_t)(r0 + lrow) * (NH*DIM) + lc;
    const float* Brow = WO   + (size_t)(n0 + lrow) * (NH*DIM) + lc;

    float acc[4][4] = {};
    for (int c0 = 0; c0 < NH*DIM; c0 += 16) {
        float4 av = *(const float4*)(Arow + c0);
        float4 bv = *(const float4*)(Brow + c0);
        __syncthreads();
        As[lc+0][lrow]=av.x; As[lc+1][lrow]=av.y; As[lc+2][lrow]=av.z; As[lc+3][lrow]=av.w;
        Bs[lc+0][lrow]=bv.x; Bs[lc+1][lrow]=bv.y; Bs[lc+2][lrow]=bv.z; Bs[lc+3][lrow]=bv.w;
        __syncthreads();
        #pragma unroll
        for (int k = 0; k < 16; ++k) {
            float4 a  = *(const float4*)&As[k][ty*4];
            float4 b4 = *(const float4*)&Bs[k][tx*4];
            const float aa[4] = {a.x, a.y, a.z, a.w};
            const float bb[4] = {b4.x, b4.y, b4.z, b4.w};
            #pragma unroll
            for (int i = 0; i < 4; ++i)
                #pragma unroll
                for (int j = 0; j < 4; ++j)
                    acc[i][j] = fmaf(aa[i], bb[j], acc[i][j]);
        }
    }
    #pragma unroll
    for (int i = 0; i < 4; ++i) {
        const int rr = r0 + ty*4 + i;
        const int b = rr >> 10, s = rr & (SEQ - 1);
        const int e = n0 + tx*4;
        float4 o = make_float4(acc[i][0] + bias[e+0], acc[i][1] + bias[e+1],
                               acc[i][2] + bias[e+2], acc[i][3] + bias[e+3]);
        *(float4*)&out[(size_t)s*(BSZ*DIM) + (size_t)b*DIM + e] = o;
    }
}

// ---------------------------------------------------------------------------
extern "C" void kernel_launch(void* const* d_in, const int* in_sizes, int n_in,
                              void* d_out, int out_size, void* d_ws, size_t ws_size,
                              hipStream_t stream)
{
    const float* x   = (const float*)d_in[0];
    const float* WKw = (const float*)d_in[1];
    const float* WKb = (const float*)d_in[2];
    const float* WVw = (const float*)d_in[3];
    const float* WVb = (const float*)d_in[4];
    const float* WQw = (const float*)d_in[5];
    const float* WQb = (const float*)d_in[6];
    const float* WOw = (const float*)d_in[7];
    const float* WOb = (const float*)d_in[8];
    float* out = (float*)d_out;

    // Workspace layout (floats). Total ~201.4 MB.
    float* ws    = (float*)d_ws;
    float* Kp    = ws;                       // [2][4][1024][512]  (b,i,t,d)
    float* Vp    = Kp + PROJ_ELEMS;          // [2][4][1024][512]
    float* Qp    = Vp + PROJ_ELEMS;          // [2][4][1024][512]  (b,h,s,d)
    float* P     = Qp + PROJ_ELEMS;          // [2][4][4096][1024] (b,h,j,s)
    float* denom = P + P_ELEMS;              // [2][4][1024]
    float* Opre  = denom + (size_t)BSZ*NH*SEQ; // [2][1024][2048]  (b,s,h*512+d)

    hipMemsetAsync(denom, 0, (size_t)BSZ*NH*SEQ*sizeof(float), stream);

    dim3 blk(256);
    proj_kernel<<<dim3(32, 32), blk, 0, stream>>>(x, WKw, WKb, Kp);
    proj_kernel<<<dim3(32, 32), blk, 0, stream>>>(x, WVw, WVb, Vp);
    proj_kernel<<<dim3(32, 32), blk, 0, stream>>>(x, WQw, WQb, Qp);
    scores_kernel<<<dim3(8, 32, 8), blk, 0, stream>>>(Kp, Qp, P, denom);
    pv_kernel<<<dim3(8, 16, 8), blk, 0, stream>>>(P, Vp, denom, Opre);
    outproj_kernel<<<dim3(8, 32), blk, 0, stream>>>(Opre, WOw, WOb, out);
}